// Round 8
// baseline (365.841 us; speedup 1.0000x reference)
//
#include <hip/hip_runtime.h>

#define N_NODES 50000
#define E_EDGES 800000
#define E2      (2 * E_EDGES)
#define D_DIM   200
#define C_CLS   10
#define NB_SCAN   ((N_NODES + 255) / 256)   // 196 scan blocks
#define NB_BUCKET ((N_NODES + 255) / 256)   // 196 buckets, 256 rows each (r>>8)
#define BATCH     4096                       // edges per phase-B block (32 KB LDS stash)
#define CSHIFT    12                         // col chunk = col >> 12 (4096 cols = 1.6 MB W0h)
#define KCH       13                         // ceil(50000 / 4096)

static __device__ __forceinline__ unsigned short f2bf(float f) {
    unsigned u = __float_as_uint(f);
    return (unsigned short)((u + 0x7FFFu + ((u >> 16) & 1u)) >> 16);   // RNE
}
static __device__ __forceinline__ float bf_lo(unsigned u) {
    return __uint_as_float(u << 16);
}
static __device__ __forceinline__ float bf_hi(unsigned u) {
    return __uint_as_float(u & 0xFFFF0000u);
}

// ---------------------------------------------------------------------------
// W0 fp32 -> bf16 (RNE), 4 elems/thread. First NB_SCAN blocks also zero cnt.
// ---------------------------------------------------------------------------
__global__ __launch_bounds__(256) void convert_w0_kernel(const float* __restrict__ W0,
                                                         unsigned short* __restrict__ W0h,
                                                         int* __restrict__ cnt) {
    if (blockIdx.x < NB_SCAN) {
        int j = blockIdx.x * 256 + threadIdx.x;
        if (j < N_NODES) cnt[j] = 0;
    }
    int i = (blockIdx.x * 256 + threadIdx.x) * 4;
    if (i >= N_NODES * D_DIM) return;
    float4 f = *(const float4*)(W0 + i);
    uint2 p;
    p.x = (unsigned)f2bf(f.x) | ((unsigned)f2bf(f.y) << 16);
    p.y = (unsigned)f2bf(f.z) | ((unsigned)f2bf(f.w) << 16);
    *(uint2*)(W0h + i) = p;
}

// ---------------------------------------------------------------------------
// CSR build: per-row counts -> hierarchical scan -> row_ptr (proven r4/r5/r7)
// ---------------------------------------------------------------------------
__global__ void count_edges_kernel(const int* __restrict__ rows0,
                                   const int* __restrict__ rows1,
                                   int* __restrict__ cnt) {
    int e = blockIdx.x * blockDim.x + threadIdx.x;
    if (e >= E2) return;
    int r = (e < E_EDGES) ? rows0[e] : rows1[e - E_EDGES];
    atomicAdd(&cnt[r], 1);
}

__global__ __launch_bounds__(256) void scan1_kernel(const int* __restrict__ cnt,
                                                    int* __restrict__ incl,
                                                    int* __restrict__ bsum) {
    const int i = blockIdx.x * 256 + threadIdx.x;
    const int lane = threadIdx.x & 63;
    const int w = threadIdx.x >> 6;
    int v = (i < N_NODES) ? cnt[i] : 0;
#pragma unroll
    for (int off = 1; off < 64; off <<= 1) {
        int t = __shfl_up(v, off, 64);
        if (lane >= off) v += t;
    }
    __shared__ int ws[4];
    if (lane == 63) ws[w] = v;
    __syncthreads();
    if (threadIdx.x == 0) {
        int s = 0;
#pragma unroll
        for (int k = 0; k < 4; ++k) { int t = ws[k]; ws[k] = s; s += t; }
    }
    __syncthreads();
    v += ws[w];
    if (i < N_NODES) incl[i] = v;
    if (threadIdx.x == 255) bsum[blockIdx.x] = v;
}

__global__ __launch_bounds__(64) void scan2_kernel(int* __restrict__ bsum,
                                                   int* __restrict__ row_ptr) {
    const int lane = threadIdx.x;
    int carry = 0;
    for (int base = 0; base < NB_SCAN; base += 64) {
        int idx = base + lane;
        int v = (idx < NB_SCAN) ? bsum[idx] : 0;
        int orig = v;
#pragma unroll
        for (int off = 1; off < 64; off <<= 1) {
            int t = __shfl_up(v, off, 64);
            if (lane >= off) v += t;
        }
        int chunk_total = __shfl(v, 63, 64);
        int excl = v - orig + carry;
        if (idx < NB_SCAN) bsum[idx] = excl;
        carry += chunk_total;
    }
    if (lane == 0) row_ptr[N_NODES] = carry;
}

__global__ __launch_bounds__(256) void scan3_kernel(const int* __restrict__ cnt,
                                                    const int* __restrict__ incl,
                                                    const int* __restrict__ bsum,
                                                    int* __restrict__ row_ptr,
                                                    int* __restrict__ bcur) {
    int i = blockIdx.x * 256 + threadIdx.x;
    if (i >= N_NODES) return;
    int ex = incl[i] - cnt[i] + bsum[blockIdx.x];
    row_ptr[i] = ex;
    if (threadIdx.x == 0) bcur[blockIdx.x] = ex;   // i == blockIdx.x<<8 < N
}

// ---------------------------------------------------------------------------
// Bucket scatter (proven r7): LDS stash + per-bucket contiguous runs.
// ---------------------------------------------------------------------------
__global__ __launch_bounds__(256) void bucket_scatter_kernel(
        const int* __restrict__ rows0, const int* __restrict__ cols0,
        const float* __restrict__ vals0,
        const int* __restrict__ rows1, const int* __restrict__ cols1,
        const float* __restrict__ vals1,
        int* __restrict__ bcur,
        int2* __restrict__ stage) {
    __shared__ int cntL[NB_BUCKET];
    __shared__ int baseL[NB_BUCKET];
    __shared__ int offL[NB_BUCKET];
    __shared__ int2 recL[BATCH];            // 32 KB
    const int tid = threadIdx.x;
    const int e0 = blockIdx.x * BATCH;

    for (int b = tid; b < NB_BUCKET; b += 256) cntL[b] = 0;
    __syncthreads();

#pragma unroll
    for (int k = 0; k < BATCH / 256; ++k) {
        int idx = k * 256 + tid;
        int e = e0 + idx;
        if (e < E2) {
            int r, c;
            float v;
            if (e < E_EDGES) {
                r = rows0[e]; c = cols0[e]; v = vals0[e];
            } else {
                int e1 = e - E_EDGES;
                r = rows1[e1]; c = cols1[e1]; v = vals1[e1];
            }
            recL[idx] = make_int2((int)((unsigned)r | ((unsigned)c << 16)),
                                  __float_as_int(v));
            atomicAdd(&cntL[r >> 8], 1);
        }
    }
    __syncthreads();

    for (int b = tid; b < NB_BUCKET; b += 256) {
        int c = cntL[b];
        baseL[b] = (c > 0) ? atomicAdd(&bcur[b], c) : 0;
        offL[b] = 0;
    }
    __syncthreads();

#pragma unroll
    for (int k = 0; k < BATCH / 256; ++k) {
        int idx = k * 256 + tid;
        int e = e0 + idx;
        if (e < E2) {
            int2 rec = recL[idx];
            int b = (int)(((unsigned)rec.x & 0xFFFFu) >> 8);
            int pos = baseL[b] + atomicAdd(&offL[b], 1);
            stage[pos] = rec;
        }
    }
}

// ---------------------------------------------------------------------------
// Bucket sort, col-chunked: one block per bucket. Orders each row's edges by
// column chunk (col>>12) so the SpMM gather walks W0h in ~1.6 MB windows —
// all concurrent waves hit the same L2-resident slice. Within-row edge order
// is mathematically irrelevant (fp sum order only).
// Pass A: histogram 256 rows x KCH chunks. Per-thread scan (its own row,
// seeded by row_ptr[row]). Pass B: place.
// ---------------------------------------------------------------------------
__global__ __launch_bounds__(256) void bucket_sort_kernel(
        const int* __restrict__ row_ptr,
        const int2* __restrict__ stage,
        int2* __restrict__ cv) {
    __shared__ int bins[256 * KCH];          // 13.3 KB: histogram, then cursors
    const int b = blockIdx.x;
    const int tid = threadIdx.x;

    for (int i = tid; i < 256 * KCH; i += 256) bins[i] = 0;
    __syncthreads();

    const int beg = row_ptr[min(b << 8, N_NODES)];
    const int end = row_ptr[min((b + 1) << 8, N_NODES)];

    // Pass A: per-(row,chunk) histogram.
    for (int i = beg + tid; i < end; i += 256) {
        unsigned u = (unsigned)stage[i].x;
        int r = (int)(u & 255u);             // row within bucket
        int ch = (int)((u >> 16) >> CSHIFT); // col chunk
        atomicAdd(&bins[r * KCH + ch], 1);
    }
    __syncthreads();

    // Per-thread sequential scan over this row's KCH chunk counts -> cursors.
    const int row = (b << 8) + tid;
    int base = (row < N_NODES) ? row_ptr[row] : 0;
    int mycur[KCH];
#pragma unroll
    for (int k = 0; k < KCH; ++k) {
        mycur[k] = base;
        base += bins[tid * KCH + k];
    }
    __syncthreads();                          // all reads of bins done
#pragma unroll
    for (int k = 0; k < KCH; ++k) bins[tid * KCH + k] = mycur[k];
    __syncthreads();

    // Pass B: place records in (row, col-chunk) order.
    for (int i = beg + tid; i < end; i += 256) {
        int2 rec = stage[i];
        unsigned u = (unsigned)rec.x;
        int r = (int)(u & 255u);
        int c = (int)(u >> 16);
        int pos = atomicAdd(&bins[r * KCH + (c >> CSHIFT)], 1);
        cv[pos] = make_int2(c, rec.y);
    }
}

// ---------------------------------------------------------------------------
// Fused layer 0 (proven r5/r7): per node n,
//   t = relu( sum_e v_e * W0h[c_e,:] + s0 * W0h[n,:] ); g[n,:] = t @ W1
// ---------------------------------------------------------------------------
__global__ __launch_bounds__(256) void spmm_layer0_fused_kernel(
        const int*  __restrict__ row_ptr,
        const int2* __restrict__ cv,
        const unsigned short* __restrict__ W0h,
        const float* __restrict__ W1,
        const float* __restrict__ eps0,
        float* __restrict__ g) {
    __shared__ float W1s[D_DIM * C_CLS];
    for (int i = threadIdx.x; i < D_DIM * C_CLS; i += blockDim.x) W1s[i] = W1[i];
    __syncthreads();

    const int lane = threadIdx.x & 63;
    const int n = __builtin_amdgcn_readfirstlane(blockIdx.x * 4 + (threadIdx.x >> 6));
    if (n >= N_NODES) return;
    const float s0 = 0.1f * (1.0f + eps0[0]);
    const bool act = (lane < 50);
    const uint2* __restrict__ F = (const uint2*)W0h;

    const int beg  = row_ptr[n];
    const int endp = row_ptr[n + 1];
    float a0 = 0.f, a1 = 0.f, a2 = 0.f, a3 = 0.f;

    int e = beg;
    for (; e + 4 <= endp; e += 4) {
        int2 p0 = cv[e], p1 = cv[e + 1], p2 = cv[e + 2], p3 = cv[e + 3];
        if (act) {
            uint2 u0 = F[(size_t)p0.x * 50 + lane];
            uint2 u1 = F[(size_t)p1.x * 50 + lane];
            uint2 u2 = F[(size_t)p2.x * 50 + lane];
            uint2 u3 = F[(size_t)p3.x * 50 + lane];
            float v0 = __int_as_float(p0.y), v1 = __int_as_float(p1.y);
            float v2 = __int_as_float(p2.y), v3 = __int_as_float(p3.y);
            a0 += v0 * bf_lo(u0.x) + v1 * bf_lo(u1.x) + v2 * bf_lo(u2.x) + v3 * bf_lo(u3.x);
            a1 += v0 * bf_hi(u0.x) + v1 * bf_hi(u1.x) + v2 * bf_hi(u2.x) + v3 * bf_hi(u3.x);
            a2 += v0 * bf_lo(u0.y) + v1 * bf_lo(u1.y) + v2 * bf_lo(u2.y) + v3 * bf_lo(u3.y);
            a3 += v0 * bf_hi(u0.y) + v1 * bf_hi(u1.y) + v2 * bf_hi(u2.y) + v3 * bf_hi(u3.y);
        }
    }
    for (; e < endp; ++e) {
        int2 p = cv[e];
        if (act) {
            uint2 u = F[(size_t)p.x * 50 + lane];
            float v = __int_as_float(p.y);
            a0 += v * bf_lo(u.x);
            a1 += v * bf_hi(u.x);
            a2 += v * bf_lo(u.y);
            a3 += v * bf_hi(u.y);
        }
    }

    float o[C_CLS];
#pragma unroll
    for (int k = 0; k < C_CLS; ++k) o[k] = 0.f;

    if (act) {
        uint2 w = F[(size_t)n * 50 + lane];
        a0 = fmaxf(a0 + s0 * bf_lo(w.x), 0.f);
        a1 = fmaxf(a1 + s0 * bf_hi(w.x), 0.f);
        a2 = fmaxf(a2 + s0 * bf_lo(w.y), 0.f);
        a3 = fmaxf(a3 + s0 * bf_hi(w.y), 0.f);
        const int d = lane * 4;
#pragma unroll
        for (int k = 0; k < C_CLS; ++k) {
            o[k] = a0 * W1s[(d + 0) * C_CLS + k]
                 + a1 * W1s[(d + 1) * C_CLS + k]
                 + a2 * W1s[(d + 2) * C_CLS + k]
                 + a3 * W1s[(d + 3) * C_CLS + k];
        }
    }

#pragma unroll
    for (int k = 0; k < C_CLS; ++k) {
        for (int off = 32; off > 0; off >>= 1)
            o[k] += __shfl_xor(o[k], off, 64);
    }

    if (lane == 0) {
        float* gp = g + (size_t)n * C_CLS;
#pragma unroll
        for (int k = 0; k < C_CLS; ++k) gp[k] = o[k];
    }
}

// ---------------------------------------------------------------------------
// Light layer 1 (proven r5/r7): out[n,:] = sum_e v_e * g[c_e,:] + s1*g[n,:]
// ---------------------------------------------------------------------------
__global__ __launch_bounds__(256) void spmm_layer1_light_kernel(
        const int*  __restrict__ row_ptr,
        const int2* __restrict__ cv,
        const float* __restrict__ g,
        const float* __restrict__ eps1,
        float* __restrict__ out) {
    const int lane = threadIdx.x & 63;
    const int n = __builtin_amdgcn_readfirstlane(blockIdx.x * 4 + (threadIdx.x >> 6));
    if (n >= N_NODES) return;
    const int grp = lane / 10;          // 0..5 active, 6 for lanes 60-63 (idle)
    const int d   = lane - grp * 10;    // 0..9
    const float s1 = 0.1f * (1.0f + eps1[0]);

    const int beg  = row_ptr[n];
    const int endp = row_ptr[n + 1];
    float acc = 0.f;

    for (int base = beg; base < endp; base += 6) {
        int e = base + grp;
        if (grp < 6 && e < endp) {
            int2 p = cv[e];
            acc += __int_as_float(p.y) * g[(size_t)p.x * C_CLS + d];
        }
    }

    float t;
    t = __shfl(acc, lane + 10, 64); if (lane < 50) acc += t;
    t = __shfl(acc, lane + 20, 64); if (lane < 30) acc += t;
    t = __shfl(acc, lane + 40, 64); if (lane < 10) acc += t;

    if (lane < 10) {
        out[(size_t)n * C_CLS + d] = acc + s1 * g[(size_t)n * C_CLS + d];
    }
}

// ---------------------------------------------------------------------------
extern "C" void kernel_launch(void* const* d_in, const int* in_sizes, int n_in,
                              void* d_out, int out_size, void* d_ws, size_t ws_size,
                              hipStream_t stream) {
    // setup_inputs order: x, rows0, cols0, vals0, rows1, cols1, vals1, W0, W1, eps0, eps1
    const int*   rows0 = (const int*)d_in[1];
    const int*   cols0 = (const int*)d_in[2];
    const float* vals0 = (const float*)d_in[3];
    const int*   rows1 = (const int*)d_in[4];
    const int*   cols1 = (const int*)d_in[5];
    const float* vals1 = (const float*)d_in[6];
    const float* W0    = (const float*)d_in[7];
    const float* W1    = (const float*)d_in[8];
    const float* eps0  = (const float*)d_in[9];
    const float* eps1  = (const float*)d_in[10];
    float* out = (float*)d_out;

    char* ws = (char*)d_ws;
    size_t off = 0;
    auto alloc = [&](size_t bytes) {
        void* p = ws + off;
        off += (bytes + 255) & ~(size_t)255;
        return p;
    };
    unsigned short* W0h = (unsigned short*)alloc((size_t)N_NODES * D_DIM * 2);  // 20 MB
    float* g     = (float*)alloc((size_t)N_NODES * C_CLS * 4);                  // 2 MB
    int* cnt     = (int*)alloc((size_t)N_NODES * 4);
    int* incl    = (int*)alloc((size_t)N_NODES * 4);
    int* bsum    = (int*)alloc((size_t)NB_SCAN * 4);
    int* row_ptr = (int*)alloc((size_t)(N_NODES + 1) * 4);
    int* bcur    = (int*)alloc((size_t)NB_BUCKET * 4);
    int2* cv     = (int2*)alloc((size_t)E2 * 8);                                // 12.8 MB
    int2* stage  = (int2*)alloc((size_t)E2 * 8);                                // 12.8 MB
    (void)ws_size;

    convert_w0_kernel<<<(N_NODES * D_DIM / 4 + 255) / 256, 256, 0, stream>>>(W0, W0h, cnt);
    count_edges_kernel<<<(E2 + 255) / 256, 256, 0, stream>>>(rows0, rows1, cnt);
    scan1_kernel<<<NB_SCAN, 256, 0, stream>>>(cnt, incl, bsum);
    scan2_kernel<<<1, 64, 0, stream>>>(bsum, row_ptr);
    scan3_kernel<<<NB_SCAN, 256, 0, stream>>>(cnt, incl, bsum, row_ptr, bcur);
    bucket_scatter_kernel<<<(E2 + BATCH - 1) / BATCH, 256, 0, stream>>>(
        rows0, cols0, vals0, rows1, cols1, vals1, bcur, stage);
    bucket_sort_kernel<<<NB_BUCKET, 256, 0, stream>>>(row_ptr, stage, cv);

    const int spmm_grid = (N_NODES + 3) / 4;   // 4 waves/block, 1 wave per node
    spmm_layer0_fused_kernel<<<spmm_grid, 256, 0, stream>>>(
        row_ptr, cv, W0h, W1, eps0, g);
    spmm_layer1_light_kernel<<<spmm_grid, 256, 0, stream>>>(
        row_ptr, cv, g, eps1, out);
}

// Round 9
// 349.245 us; speedup vs baseline: 1.0475x; 1.0475x over previous
//
#include <hip/hip_runtime.h>

#define N_NODES 50000
#define E_EDGES 800000
#define E2      (2 * E_EDGES)
#define D_DIM   200
#define C_CLS   10
#define NB_SCAN   ((N_NODES + 255) / 256)   // 196 scan blocks
#define NB_BUCKET ((N_NODES + 255) / 256)   // 196 buckets, 256 rows each (r>>8)
#define BATCH     4096                       // edges per phase-B block (32 KB LDS stash)

static __device__ __forceinline__ unsigned short f2bf(float f) {
    unsigned u = __float_as_uint(f);
    return (unsigned short)((u + 0x7FFFu + ((u >> 16) & 1u)) >> 16);   // RNE
}
static __device__ __forceinline__ float bf_lo(unsigned u) {
    return __uint_as_float(u << 16);
}
static __device__ __forceinline__ float bf_hi(unsigned u) {
    return __uint_as_float(u & 0xFFFF0000u);
}

// ---------------------------------------------------------------------------
// W0 fp32 -> bf16 (RNE), 4 elems/thread. First NB_SCAN blocks also zero cnt.
// ---------------------------------------------------------------------------
__global__ __launch_bounds__(256) void convert_w0_kernel(const float* __restrict__ W0,
                                                         unsigned short* __restrict__ W0h,
                                                         int* __restrict__ cnt) {
    if (blockIdx.x < NB_SCAN) {
        int j = blockIdx.x * 256 + threadIdx.x;
        if (j < N_NODES) cnt[j] = 0;
    }
    int i = (blockIdx.x * 256 + threadIdx.x) * 4;
    if (i >= N_NODES * D_DIM) return;
    float4 f = *(const float4*)(W0 + i);
    uint2 p;
    p.x = (unsigned)f2bf(f.x) | ((unsigned)f2bf(f.y) << 16);
    p.y = (unsigned)f2bf(f.z) | ((unsigned)f2bf(f.w) << 16);
    *(uint2*)(W0h + i) = p;
}

// ---------------------------------------------------------------------------
// CSR build: per-row counts -> hierarchical scan -> row_ptr (proven r4/r5/r7)
// ---------------------------------------------------------------------------
__global__ void count_edges_kernel(const int* __restrict__ rows0,
                                   const int* __restrict__ rows1,
                                   int* __restrict__ cnt) {
    int e = blockIdx.x * blockDim.x + threadIdx.x;
    if (e >= E2) return;
    int r = (e < E_EDGES) ? rows0[e] : rows1[e - E_EDGES];
    atomicAdd(&cnt[r], 1);
}

__global__ __launch_bounds__(256) void scan1_kernel(const int* __restrict__ cnt,
                                                    int* __restrict__ incl,
                                                    int* __restrict__ bsum) {
    const int i = blockIdx.x * 256 + threadIdx.x;
    const int lane = threadIdx.x & 63;
    const int w = threadIdx.x >> 6;
    int v = (i < N_NODES) ? cnt[i] : 0;
#pragma unroll
    for (int off = 1; off < 64; off <<= 1) {
        int t = __shfl_up(v, off, 64);
        if (lane >= off) v += t;
    }
    __shared__ int ws[4];
    if (lane == 63) ws[w] = v;
    __syncthreads();
    if (threadIdx.x == 0) {
        int s = 0;
#pragma unroll
        for (int k = 0; k < 4; ++k) { int t = ws[k]; ws[k] = s; s += t; }
    }
    __syncthreads();
    v += ws[w];
    if (i < N_NODES) incl[i] = v;
    if (threadIdx.x == 255) bsum[blockIdx.x] = v;
}

__global__ __launch_bounds__(64) void scan2_kernel(int* __restrict__ bsum,
                                                   int* __restrict__ row_ptr) {
    const int lane = threadIdx.x;
    int carry = 0;
    for (int base = 0; base < NB_SCAN; base += 64) {
        int idx = base + lane;
        int v = (idx < NB_SCAN) ? bsum[idx] : 0;
        int orig = v;
#pragma unroll
        for (int off = 1; off < 64; off <<= 1) {
            int t = __shfl_up(v, off, 64);
            if (lane >= off) v += t;
        }
        int chunk_total = __shfl(v, 63, 64);
        int excl = v - orig + carry;
        if (idx < NB_SCAN) bsum[idx] = excl;
        carry += chunk_total;
    }
    if (lane == 0) row_ptr[N_NODES] = carry;
}

__global__ __launch_bounds__(256) void scan3_kernel(const int* __restrict__ cnt,
                                                    const int* __restrict__ incl,
                                                    const int* __restrict__ bsum,
                                                    int* __restrict__ row_ptr,
                                                    int* __restrict__ bcur) {
    int i = blockIdx.x * 256 + threadIdx.x;
    if (i >= N_NODES) return;
    int ex = incl[i] - cnt[i] + bsum[blockIdx.x];
    row_ptr[i] = ex;
    if (threadIdx.x == 0) bcur[blockIdx.x] = ex;   // i == blockIdx.x<<8 < N
}

// ---------------------------------------------------------------------------
// Bucket scatter (proven r7): LDS stash + per-bucket contiguous runs.
// ---------------------------------------------------------------------------
__global__ __launch_bounds__(256) void bucket_scatter_kernel(
        const int* __restrict__ rows0, const int* __restrict__ cols0,
        const float* __restrict__ vals0,
        const int* __restrict__ rows1, const int* __restrict__ cols1,
        const float* __restrict__ vals1,
        int* __restrict__ bcur,
        int2* __restrict__ stage) {
    __shared__ int cntL[NB_BUCKET];
    __shared__ int baseL[NB_BUCKET];
    __shared__ int offL[NB_BUCKET];
    __shared__ int2 recL[BATCH];            // 32 KB
    const int tid = threadIdx.x;
    const int e0 = blockIdx.x * BATCH;

    for (int b = tid; b < NB_BUCKET; b += 256) cntL[b] = 0;
    __syncthreads();

#pragma unroll
    for (int k = 0; k < BATCH / 256; ++k) {
        int idx = k * 256 + tid;
        int e = e0 + idx;
        if (e < E2) {
            int r, c;
            float v;
            if (e < E_EDGES) {
                r = rows0[e]; c = cols0[e]; v = vals0[e];
            } else {
                int e1 = e - E_EDGES;
                r = rows1[e1]; c = cols1[e1]; v = vals1[e1];
            }
            recL[idx] = make_int2((int)((unsigned)r | ((unsigned)c << 16)),
                                  __float_as_int(v));
            atomicAdd(&cntL[r >> 8], 1);
        }
    }
    __syncthreads();

    for (int b = tid; b < NB_BUCKET; b += 256) {
        int c = cntL[b];
        baseL[b] = (c > 0) ? atomicAdd(&bcur[b], c) : 0;
        offL[b] = 0;
    }
    __syncthreads();

#pragma unroll
    for (int k = 0; k < BATCH / 256; ++k) {
        int idx = k * 256 + tid;
        int e = e0 + idx;
        if (e < E2) {
            int2 rec = recL[idx];
            int b = (int)(((unsigned)rec.x & 0xFFFFu) >> 8);
            int pos = baseL[b] + atomicAdd(&offL[b], 1);
            stage[pos] = rec;
        }
    }
}

// ---------------------------------------------------------------------------
// Bucket sort (proven r4/r5/r7): one block per bucket; place records into
// final CSR order via LDS per-row cursors.
// ---------------------------------------------------------------------------
__global__ __launch_bounds__(256) void bucket_sort_kernel(
        const int* __restrict__ row_ptr,
        const int2* __restrict__ stage,
        int2* __restrict__ cv) {
    __shared__ int lcur[256];
    const int b = blockIdx.x;
    const int tid = threadIdx.x;
    const int row = (b << 8) + tid;
    lcur[tid] = (row < N_NODES) ? row_ptr[row] : 0;
    __syncthreads();

    const int beg = row_ptr[min(b << 8, N_NODES)];
    const int end = row_ptr[min((b + 1) << 8, N_NODES)];
    for (int i = beg + tid; i < end; i += 256) {
        int2 rec = stage[i];
        unsigned u = (unsigned)rec.x;
        int r = (int)(u & 0xFFFFu);
        int c = (int)(u >> 16);
        int pos = atomicAdd(&lcur[r & 255], 1);
        cv[pos] = make_int2(c, rec.y);
    }
}

// ---------------------------------------------------------------------------
// Fused layer 0, unroll-8 for memory-level parallelism: per node n,
//   t = relu( sum_e v_e * W0h[c_e,:] + s0 * W0h[n,:] ); g[n,:] = t @ W1
// 8 independent 400 B gathers in flight per wave (was 4) to cover the
// ~400-600 cyc L3-hit latency. VGPR ~50, still 8 waves/SIMD.
// ---------------------------------------------------------------------------
__global__ __launch_bounds__(256) void spmm_layer0_fused_kernel(
        const int*  __restrict__ row_ptr,
        const int2* __restrict__ cv,
        const unsigned short* __restrict__ W0h,
        const float* __restrict__ W1,
        const float* __restrict__ eps0,
        float* __restrict__ g) {
    __shared__ float W1s[D_DIM * C_CLS];
    for (int i = threadIdx.x; i < D_DIM * C_CLS; i += blockDim.x) W1s[i] = W1[i];
    __syncthreads();

    const int lane = threadIdx.x & 63;
    const int n = __builtin_amdgcn_readfirstlane(blockIdx.x * 4 + (threadIdx.x >> 6));
    if (n >= N_NODES) return;
    const float s0 = 0.1f * (1.0f + eps0[0]);
    const bool act = (lane < 50);
    const uint2* __restrict__ F = (const uint2*)W0h;

    const int beg  = row_ptr[n];
    const int endp = row_ptr[n + 1];
    float a0 = 0.f, a1 = 0.f, a2 = 0.f, a3 = 0.f;

    int e = beg;
    for (; e + 8 <= endp; e += 8) {
        int2 p0 = cv[e],     p1 = cv[e + 1], p2 = cv[e + 2], p3 = cv[e + 3];
        int2 p4 = cv[e + 4], p5 = cv[e + 5], p6 = cv[e + 6], p7 = cv[e + 7];
        if (act) {
            uint2 u0 = F[(size_t)p0.x * 50 + lane];
            uint2 u1 = F[(size_t)p1.x * 50 + lane];
            uint2 u2 = F[(size_t)p2.x * 50 + lane];
            uint2 u3 = F[(size_t)p3.x * 50 + lane];
            uint2 u4 = F[(size_t)p4.x * 50 + lane];
            uint2 u5 = F[(size_t)p5.x * 50 + lane];
            uint2 u6 = F[(size_t)p6.x * 50 + lane];
            uint2 u7 = F[(size_t)p7.x * 50 + lane];
            float v0 = __int_as_float(p0.y), v1 = __int_as_float(p1.y);
            float v2 = __int_as_float(p2.y), v3 = __int_as_float(p3.y);
            float v4 = __int_as_float(p4.y), v5 = __int_as_float(p5.y);
            float v6 = __int_as_float(p6.y), v7 = __int_as_float(p7.y);
            a0 += v0 * bf_lo(u0.x) + v1 * bf_lo(u1.x) + v2 * bf_lo(u2.x) + v3 * bf_lo(u3.x)
                + v4 * bf_lo(u4.x) + v5 * bf_lo(u5.x) + v6 * bf_lo(u6.x) + v7 * bf_lo(u7.x);
            a1 += v0 * bf_hi(u0.x) + v1 * bf_hi(u1.x) + v2 * bf_hi(u2.x) + v3 * bf_hi(u3.x)
                + v4 * bf_hi(u4.x) + v5 * bf_hi(u5.x) + v6 * bf_hi(u6.x) + v7 * bf_hi(u7.x);
            a2 += v0 * bf_lo(u0.y) + v1 * bf_lo(u1.y) + v2 * bf_lo(u2.y) + v3 * bf_lo(u3.y)
                + v4 * bf_lo(u4.y) + v5 * bf_lo(u5.y) + v6 * bf_lo(u6.y) + v7 * bf_lo(u7.y);
            a3 += v0 * bf_hi(u0.y) + v1 * bf_hi(u1.y) + v2 * bf_hi(u2.y) + v3 * bf_hi(u3.y)
                + v4 * bf_hi(u4.y) + v5 * bf_hi(u5.y) + v6 * bf_hi(u6.y) + v7 * bf_hi(u7.y);
        }
    }
    for (; e + 4 <= endp; e += 4) {
        int2 p0 = cv[e], p1 = cv[e + 1], p2 = cv[e + 2], p3 = cv[e + 3];
        if (act) {
            uint2 u0 = F[(size_t)p0.x * 50 + lane];
            uint2 u1 = F[(size_t)p1.x * 50 + lane];
            uint2 u2 = F[(size_t)p2.x * 50 + lane];
            uint2 u3 = F[(size_t)p3.x * 50 + lane];
            float v0 = __int_as_float(p0.y), v1 = __int_as_float(p1.y);
            float v2 = __int_as_float(p2.y), v3 = __int_as_float(p3.y);
            a0 += v0 * bf_lo(u0.x) + v1 * bf_lo(u1.x) + v2 * bf_lo(u2.x) + v3 * bf_lo(u3.x);
            a1 += v0 * bf_hi(u0.x) + v1 * bf_hi(u1.x) + v2 * bf_hi(u2.x) + v3 * bf_hi(u3.x);
            a2 += v0 * bf_lo(u0.y) + v1 * bf_lo(u1.y) + v2 * bf_lo(u2.y) + v3 * bf_lo(u3.y);
            a3 += v0 * bf_hi(u0.y) + v1 * bf_hi(u1.y) + v2 * bf_hi(u2.y) + v3 * bf_hi(u3.y);
        }
    }
    for (; e < endp; ++e) {
        int2 p = cv[e];
        if (act) {
            uint2 u = F[(size_t)p.x * 50 + lane];
            float v = __int_as_float(p.y);
            a0 += v * bf_lo(u.x);
            a1 += v * bf_hi(u.x);
            a2 += v * bf_lo(u.y);
            a3 += v * bf_hi(u.y);
        }
    }

    float o[C_CLS];
#pragma unroll
    for (int k = 0; k < C_CLS; ++k) o[k] = 0.f;

    if (act) {
        uint2 w = F[(size_t)n * 50 + lane];
        a0 = fmaxf(a0 + s0 * bf_lo(w.x), 0.f);
        a1 = fmaxf(a1 + s0 * bf_hi(w.x), 0.f);
        a2 = fmaxf(a2 + s0 * bf_lo(w.y), 0.f);
        a3 = fmaxf(a3 + s0 * bf_hi(w.y), 0.f);
        const int d = lane * 4;
#pragma unroll
        for (int k = 0; k < C_CLS; ++k) {
            o[k] = a0 * W1s[(d + 0) * C_CLS + k]
                 + a1 * W1s[(d + 1) * C_CLS + k]
                 + a2 * W1s[(d + 2) * C_CLS + k]
                 + a3 * W1s[(d + 3) * C_CLS + k];
        }
    }

#pragma unroll
    for (int k = 0; k < C_CLS; ++k) {
        for (int off = 32; off > 0; off >>= 1)
            o[k] += __shfl_xor(o[k], off, 64);
    }

    if (lane == 0) {
        float* gp = g + (size_t)n * C_CLS;
#pragma unroll
        for (int k = 0; k < C_CLS; ++k) gp[k] = o[k];
    }
}

// ---------------------------------------------------------------------------
// Light layer 1 (proven r5/r7): out[n,:] = sum_e v_e * g[c_e,:] + s1*g[n,:]
// ---------------------------------------------------------------------------
__global__ __launch_bounds__(256) void spmm_layer1_light_kernel(
        const int*  __restrict__ row_ptr,
        const int2* __restrict__ cv,
        const float* __restrict__ g,
        const float* __restrict__ eps1,
        float* __restrict__ out) {
    const int lane = threadIdx.x & 63;
    const int n = __builtin_amdgcn_readfirstlane(blockIdx.x * 4 + (threadIdx.x >> 6));
    if (n >= N_NODES) return;
    const int grp = lane / 10;          // 0..5 active, 6 for lanes 60-63 (idle)
    const int d   = lane - grp * 10;    // 0..9
    const float s1 = 0.1f * (1.0f + eps1[0]);

    const int beg  = row_ptr[n];
    const int endp = row_ptr[n + 1];
    float acc = 0.f;

    for (int base = beg; base < endp; base += 6) {
        int e = base + grp;
        if (grp < 6 && e < endp) {
            int2 p = cv[e];
            acc += __int_as_float(p.y) * g[(size_t)p.x * C_CLS + d];
        }
    }

    float t;
    t = __shfl(acc, lane + 10, 64); if (lane < 50) acc += t;
    t = __shfl(acc, lane + 20, 64); if (lane < 30) acc += t;
    t = __shfl(acc, lane + 40, 64); if (lane < 10) acc += t;

    if (lane < 10) {
        out[(size_t)n * C_CLS + d] = acc + s1 * g[(size_t)n * C_CLS + d];
    }
}

// ---------------------------------------------------------------------------
extern "C" void kernel_launch(void* const* d_in, const int* in_sizes, int n_in,
                              void* d_out, int out_size, void* d_ws, size_t ws_size,
                              hipStream_t stream) {
    // setup_inputs order: x, rows0, cols0, vals0, rows1, cols1, vals1, W0, W1, eps0, eps1
    const int*   rows0 = (const int*)d_in[1];
    const int*   cols0 = (const int*)d_in[2];
    const float* vals0 = (const float*)d_in[3];
    const int*   rows1 = (const int*)d_in[4];
    const int*   cols1 = (const int*)d_in[5];
    const float* vals1 = (const float*)d_in[6];
    const float* W0    = (const float*)d_in[7];
    const float* W1    = (const float*)d_in[8];
    const float* eps0  = (const float*)d_in[9];
    const float* eps1  = (const float*)d_in[10];
    float* out = (float*)d_out;

    char* ws = (char*)d_ws;
    size_t off = 0;
    auto alloc = [&](size_t bytes) {
        void* p = ws + off;
        off += (bytes + 255) & ~(size_t)255;
        return p;
    };
    unsigned short* W0h = (unsigned short*)alloc((size_t)N_NODES * D_DIM * 2);  // 20 MB
    float* g     = (float*)alloc((size_t)N_NODES * C_CLS * 4);                  // 2 MB
    int* cnt     = (int*)alloc((size_t)N_NODES * 4);
    int* incl    = (int*)alloc((size_t)N_NODES * 4);
    int* bsum    = (int*)alloc((size_t)NB_SCAN * 4);
    int* row_ptr = (int*)alloc((size_t)(N_NODES + 1) * 4);
    int* bcur    = (int*)alloc((size_t)NB_BUCKET * 4);
    int2* cv     = (int2*)alloc((size_t)E2 * 8);                                // 12.8 MB
    int2* stage  = (int2*)alloc((size_t)E2 * 8);                                // 12.8 MB
    (void)ws_size;

    convert_w0_kernel<<<(N_NODES * D_DIM / 4 + 255) / 256, 256, 0, stream>>>(W0, W0h, cnt);
    count_edges_kernel<<<(E2 + 255) / 256, 256, 0, stream>>>(rows0, rows1, cnt);
    scan1_kernel<<<NB_SCAN, 256, 0, stream>>>(cnt, incl, bsum);
    scan2_kernel<<<1, 64, 0, stream>>>(bsum, row_ptr);
    scan3_kernel<<<NB_SCAN, 256, 0, stream>>>(cnt, incl, bsum, row_ptr, bcur);
    bucket_scatter_kernel<<<(E2 + BATCH - 1) / BATCH, 256, 0, stream>>>(
        rows0, cols0, vals0, rows1, cols1, vals1, bcur, stage);
    bucket_sort_kernel<<<NB_BUCKET, 256, 0, stream>>>(row_ptr, stage, cv);

    const int spmm_grid = (N_NODES + 3) / 4;   // 4 waves/block, 1 wave per node
    spmm_layer0_fused_kernel<<<spmm_grid, 256, 0, stream>>>(
        row_ptr, cv, W0h, W1, eps0, g);
    spmm_layer1_light_kernel<<<spmm_grid, 256, 0, stream>>>(
        row_ptr, cv, g, eps1, out);
}